// Round 1
// baseline (9181.730 us; speedup 1.0000x reference)
//
#include <hip/hip_runtime.h>

// Problem constants (from reference)
constexpr int B = 4, C = 32, H = 544, W = 960;
constexpr int HW = H * W;          // 522240
constexpr int NPIX = B * HW;       // 2088960

__global__ __launch_bounds__(256)
void splat_kernel(const float* __restrict__ inp,
                  const float* __restrict__ flow,
                  const float* __restrict__ metric,
                  float* __restrict__ out,    // [B*C*HW] accumulators (pre-zeroed)
                  float* __restrict__ norm)   // [B*HW] accumulators (pre-zeroed)
{
    int idx = blockIdx.x * blockDim.x + threadIdx.x;
    if (idx >= NPIX) return;
    int b = idx / HW;
    int p = idx - b * HW;
    int y = p / W;
    int x = p - y * W;

    float fx = flow[(b * 2 + 0) * HW + p];
    float fy = flow[(b * 2 + 1) * HW + p];
    float m  = __expf(metric[b * HW + p]);

    float ox = (float)x + fx;
    float oy = (float)y + fy;
    float x0f = floorf(ox), y0f = floorf(oy);
    int   x0  = (int)x0f,  y0  = (int)y0f;
    int   x1  = x0 + 1,    y1  = y0 + 1;
    float wx1 = ox - x0f, wx0 = 1.0f - wx1;
    float wy1 = oy - y0f, wy0 = 1.0f - wy1;

    // Load the 32 channel values once (coalesced across threads), pre-scaled by m.
    float v[C];
    const float* inb = inp + (size_t)b * C * HW + p;
#pragma unroll
    for (int c = 0; c < C; ++c) v[c] = inb[(size_t)c * HW] * m;

    float* outb = out + (size_t)b * C * HW;
    float* nrmb = norm + (size_t)b * HW;

    const int   cxs[4] = { x0, x1, x0, x1 };
    const int   cys[4] = { y0, y0, y1, y1 };
    const float wts[4] = { wx0 * wy0, wx1 * wy0, wx0 * wy1, wx1 * wy1 };

#pragma unroll
    for (int k = 0; k < 4; ++k) {
        int cx = cxs[k], cy = cys[k];
        if (cx < 0 || cx >= W || cy < 0 || cy >= H) continue;
        float wt = wts[k];
        int q = cy * W + cx;
        atomicAdd(&nrmb[q], m * wt);
#pragma unroll
        for (int c = 0; c < C; ++c)
            atomicAdd(&outb[(size_t)c * HW + q], v[c] * wt);
    }
}

__global__ __launch_bounds__(256)
void normalize_kernel(float* __restrict__ out,
                      const float* __restrict__ norm)
{
    // one thread per 4 consecutive elements
    int t = blockIdx.x * blockDim.x + threadIdx.x;
    long long base = (long long)t * 4;
    if (base >= (long long)B * C * HW) return;
    // channel-broadcast norm index: same (b, pixel) for all c
    long long b = base / ((long long)C * HW);
    long long q = base % HW;

    float4 o = *reinterpret_cast<float4*>(out + base);
    float4 n = *reinterpret_cast<const float4*>(norm + b * HW + q);
    o.x /= (n.x == 0.0f ? 1.0f : n.x);
    o.y /= (n.y == 0.0f ? 1.0f : n.y);
    o.z /= (n.z == 0.0f ? 1.0f : n.z);
    o.w /= (n.w == 0.0f ? 1.0f : n.w);
    *reinterpret_cast<float4*>(out + base) = o;
}

extern "C" void kernel_launch(void* const* d_in, const int* in_sizes, int n_in,
                              void* d_out, int out_size, void* d_ws, size_t ws_size,
                              hipStream_t stream) {
    const float* tenInput  = (const float*)d_in[0];
    const float* tenFlow   = (const float*)d_in[1];
    const float* tenMetric = (const float*)d_in[2];
    float* out  = (float*)d_out;
    float* norm = (float*)d_ws;

    // Zero accumulators every call (harness poisons once; we must re-init anyway).
    hipMemsetAsync(out, 0, (size_t)B * C * HW * sizeof(float), stream);
    hipMemsetAsync(norm, 0, (size_t)B * HW * sizeof(float), stream);

    {
        int threads = 256;
        int blocks = (NPIX + threads - 1) / threads;
        splat_kernel<<<blocks, threads, 0, stream>>>(tenInput, tenFlow, tenMetric, out, norm);
    }
    {
        long long total = (long long)B * C * HW / 4;
        int threads = 256;
        long long blocks = (total + threads - 1) / threads;
        normalize_kernel<<<(int)blocks, threads, 0, stream>>>(out, norm);
    }
}

// Round 2
// 4773.742 us; speedup vs baseline: 1.9234x; 1.9234x over previous
//
#include <hip/hip_runtime.h>
#include <hip/hip_fp16.h>

// Problem constants (from reference)
constexpr int B = 4, C = 32, H = 544, W = 960;
constexpr int HW = H * W;          // 522240
constexpr int NPIX = B * HW;       // 2088960
constexpr int C2 = C / 2;          // 16 packed channel-pairs
constexpr int P4 = HW / 4;         // 130560 pixel-quads per (b, c2)

// ---------- fast path: f16-packed accumulators in workspace ----------

__global__ __launch_bounds__(256)
void splat_f16(const float* __restrict__ inp,
               const float* __restrict__ flow,
               const float* __restrict__ metric,
               __half2* __restrict__ acc,   // [B*C2*HW] packed (c, c+1) accumulators, pre-zeroed
               float* __restrict__ norm)    // [B*HW] f32 norm accumulators, pre-zeroed
{
    int idx = blockIdx.x * blockDim.x + threadIdx.x;
    if (idx >= NPIX) return;
    int b = idx / HW;
    int p = idx - b * HW;
    int y = p / W;
    int x = p - y * W;

    float fx = flow[(b * 2 + 0) * HW + p];
    float fy = flow[(b * 2 + 1) * HW + p];
    float m  = __expf(metric[b * HW + p]);

    float ox = (float)x + fx;
    float oy = (float)y + fy;
    float x0f = floorf(ox), y0f = floorf(oy);
    int   x0  = (int)x0f,  y0  = (int)y0f;
    float wx1 = ox - x0f, wx0 = 1.0f - wx1;
    float wy1 = oy - y0f, wy0 = 1.0f - wy1;

    // Load 32 channel values (coalesced), pre-scaled by m.
    float vm[C];
    const float* inb = inp + (size_t)b * C * HW + p;
#pragma unroll
    for (int c = 0; c < C; ++c) vm[c] = inb[(size_t)c * HW] * m;

    __half2* accb = acc + (size_t)b * C2 * HW;
    float*   nrmb = norm + (size_t)b * HW;

    const int   cxs[4] = { x0, x0 + 1, x0,     x0 + 1 };
    const int   cys[4] = { y0, y0,     y0 + 1, y0 + 1 };
    const float wts[4] = { wx0 * wy0, wx1 * wy0, wx0 * wy1, wx1 * wy1 };

#pragma unroll
    for (int k = 0; k < 4; ++k) {
        int cx = cxs[k], cy = cys[k];
        if (cx < 0 || cx >= W || cy < 0 || cy >= H) continue;
        float wt = wts[k];
        int q = cy * W + cx;
        unsafeAtomicAdd(&nrmb[q], m * wt);
#pragma unroll
        for (int c2 = 0; c2 < C2; ++c2) {
            __half2 h = __floats2half2_rn(vm[2 * c2] * wt, vm[2 * c2 + 1] * wt);
            unsafeAtomicAdd(&accb[(size_t)c2 * HW + q], h);   // global_atomic_pk_add_f16
        }
    }
}

__global__ __launch_bounds__(256)
void normalize_f16(const __half2* __restrict__ acc,
                   const float* __restrict__ norm,
                   float* __restrict__ out)
{
    // one thread per (b, c2, pixel-quad): 16B acc load, 16B norm load, 2x16B out stores
    int t = blockIdx.x * blockDim.x + threadIdx.x;
    if (t >= B * C2 * P4) return;
    int p4   = t % P4;
    int rest = t / P4;
    int c2   = rest % C2;
    int b    = rest / C2;

    const float4 araw = *reinterpret_cast<const float4*>(
        acc + ((size_t)(b * C2 + c2)) * HW + (size_t)p4 * 4);
    float4 n = *reinterpret_cast<const float4*>(norm + (size_t)b * HW + (size_t)p4 * 4);
    float r0 = (n.x == 0.0f) ? 1.0f : 1.0f / n.x;
    float r1 = (n.y == 0.0f) ? 1.0f : 1.0f / n.y;
    float r2 = (n.z == 0.0f) ? 1.0f : 1.0f / n.z;
    float r3 = (n.w == 0.0f) ? 1.0f : 1.0f / n.w;

    __half2 h0 = *reinterpret_cast<const __half2*>(&araw.x);
    __half2 h1 = *reinterpret_cast<const __half2*>(&araw.y);
    __half2 h2 = *reinterpret_cast<const __half2*>(&araw.z);
    __half2 h3 = *reinterpret_cast<const __half2*>(&araw.w);

    float4 lo = make_float4(__low2float(h0) * r0, __low2float(h1) * r1,
                            __low2float(h2) * r2, __low2float(h3) * r3);
    float4 hi = make_float4(__high2float(h0) * r0, __high2float(h1) * r1,
                            __high2float(h2) * r2, __high2float(h3) * r3);

    float* o0 = out + ((size_t)b * C + 2 * c2)     * HW + (size_t)p4 * 4;
    float* o1 = out + ((size_t)b * C + 2 * c2 + 1) * HW + (size_t)p4 * 4;
    *reinterpret_cast<float4*>(o0) = lo;
    *reinterpret_cast<float4*>(o1) = hi;
}

// ---------- fallback path: f32 atomics straight into d_out ----------

__global__ __launch_bounds__(256)
void splat_f32(const float* __restrict__ inp,
               const float* __restrict__ flow,
               const float* __restrict__ metric,
               float* __restrict__ out,
               float* __restrict__ norm)
{
    int idx = blockIdx.x * blockDim.x + threadIdx.x;
    if (idx >= NPIX) return;
    int b = idx / HW;
    int p = idx - b * HW;
    int y = p / W;
    int x = p - y * W;

    float fx = flow[(b * 2 + 0) * HW + p];
    float fy = flow[(b * 2 + 1) * HW + p];
    float m  = __expf(metric[b * HW + p]);

    float ox = (float)x + fx, oy = (float)y + fy;
    float x0f = floorf(ox), y0f = floorf(oy);
    int x0 = (int)x0f, y0 = (int)y0f;
    float wx1 = ox - x0f, wx0 = 1.0f - wx1;
    float wy1 = oy - y0f, wy0 = 1.0f - wy1;

    float vm[C];
    const float* inb = inp + (size_t)b * C * HW + p;
#pragma unroll
    for (int c = 0; c < C; ++c) vm[c] = inb[(size_t)c * HW] * m;

    float* outb = out + (size_t)b * C * HW;
    float* nrmb = norm + (size_t)b * HW;

    const int   cxs[4] = { x0, x0 + 1, x0,     x0 + 1 };
    const int   cys[4] = { y0, y0,     y0 + 1, y0 + 1 };
    const float wts[4] = { wx0 * wy0, wx1 * wy0, wx0 * wy1, wx1 * wy1 };

#pragma unroll
    for (int k = 0; k < 4; ++k) {
        int cx = cxs[k], cy = cys[k];
        if (cx < 0 || cx >= W || cy < 0 || cy >= H) continue;
        float wt = wts[k];
        int q = cy * W + cx;
        atomicAdd(&nrmb[q], m * wt);
#pragma unroll
        for (int c = 0; c < C; ++c)
            atomicAdd(&outb[(size_t)c * HW + q], vm[c] * wt);
    }
}

__global__ __launch_bounds__(256)
void normalize_f32(float* __restrict__ out, const float* __restrict__ norm)
{
    int t = blockIdx.x * blockDim.x + threadIdx.x;
    long long base = (long long)t * 4;
    if (base >= (long long)B * C * HW) return;
    long long b = base / ((long long)C * HW);
    long long q = base % HW;

    float4 o = *reinterpret_cast<float4*>(out + base);
    float4 n = *reinterpret_cast<const float4*>(norm + b * HW + q);
    o.x /= (n.x == 0.0f ? 1.0f : n.x);
    o.y /= (n.y == 0.0f ? 1.0f : n.y);
    o.z /= (n.z == 0.0f ? 1.0f : n.z);
    o.w /= (n.w == 0.0f ? 1.0f : n.w);
    *reinterpret_cast<float4*>(out + base) = o;
}

extern "C" void kernel_launch(void* const* d_in, const int* in_sizes, int n_in,
                              void* d_out, int out_size, void* d_ws, size_t ws_size,
                              hipStream_t stream) {
    const float* tenInput  = (const float*)d_in[0];
    const float* tenFlow   = (const float*)d_in[1];
    const float* tenMetric = (const float*)d_in[2];
    float* out = (float*)d_out;

    const size_t accBytes  = (size_t)B * C2 * HW * sizeof(__half2);  // 133.7 MB
    const size_t normBytes = (size_t)NPIX * sizeof(float);           // 8.4 MB

    if (ws_size >= accBytes + normBytes) {
        __half2* acc  = (__half2*)d_ws;
        float*   norm = (float*)((char*)d_ws + accBytes);

        hipMemsetAsync(d_ws, 0, accBytes + normBytes, stream);

        int threads = 256;
        int blocks = (NPIX + threads - 1) / threads;
        splat_f16<<<blocks, threads, 0, stream>>>(tenInput, tenFlow, tenMetric, acc, norm);

        int total = B * C2 * P4;
        normalize_f16<<<(total + threads - 1) / threads, threads, 0, stream>>>(acc, norm, out);
    } else {
        float* norm = (float*)d_ws;
        hipMemsetAsync(out, 0, (size_t)B * C * HW * sizeof(float), stream);
        hipMemsetAsync(norm, 0, normBytes, stream);

        int threads = 256;
        int blocks = (NPIX + threads - 1) / threads;
        splat_f32<<<blocks, threads, 0, stream>>>(tenInput, tenFlow, tenMetric, out, norm);

        long long total = (long long)B * C * HW / 4;
        normalize_f32<<<(int)((total + threads - 1) / threads), threads, 0, stream>>>(out, norm);
    }
}

// Round 3
// 1650.821 us; speedup vs baseline: 5.5619x; 2.8917x over previous
//
#include <hip/hip_runtime.h>
#include <hip/hip_fp16.h>

// Problem constants (from reference)
constexpr int B = 4, C = 32, H = 544, W = 960;
constexpr int HW = H * W;          // 522240
constexpr int NPIX = B * HW;       // 2088960
constexpr int NPAIR = 17;          // 16 channel-pairs + 1 norm plane (lo=norm, hi=0)
constexpr int P4 = HW / 4;         // 130560 pixel-quads per plane

// Tiled splat geometry
constexpr int TX = 96, TY = 96;        // source tile
constexpr int PAD = 16;                // window halo; |flow| <= 15 stays in-window
constexpr int WX = 128, WY = 128;      // LDS window = tile + 2*PAD (power of 2!)
constexpr int CELLS = WX * WY;         // 16384
constexpr int TILES_X = (W + TX - 1) / TX;   // 10
constexpr int TILES_Y = (H + TY - 1) / TY;   // 6
constexpr int TPB = 512;

__device__ __forceinline__ void lds_add(float* a, float v) {
    (void)__hip_atomic_fetch_add(a, v, __ATOMIC_RELAXED, __HIP_MEMORY_SCOPE_WORKGROUP);
}

// ---------- fast path: LDS-privatized tiled splat, f16x2 global accumulator ----------

__global__ __launch_bounds__(TPB)
void splat_tiled(const float* __restrict__ inp,
                 const float* __restrict__ flow,
                 const float* __restrict__ metric,
                 __half2* __restrict__ acc)   // [B][NPAIR][HW] half2, pre-zeroed
{
    __shared__ float l0[CELLS];   // 64 KB
    __shared__ float l1[CELLS];   // 64 KB

    const int tile = blockIdx.x;
    const int b    = blockIdx.y;
    const int pass = blockIdx.z;              // 0..16
    const int tx0  = (tile % TILES_X) * TX;
    const int ty0  = (tile / TILES_X) * TY;
    const bool isNorm = (pass == NPAIR - 1);

    for (int i = threadIdx.x; i < CELLS; i += TPB) { l0[i] = 0.0f; l1[i] = 0.0f; }
    __syncthreads();

    const float* fxp = flow + (size_t)(b * 2 + 0) * HW;
    const float* fyp = flow + (size_t)(b * 2 + 1) * HW;
    const float* mp  = metric + (size_t)b * HW;
    const float* p0  = inp + ((size_t)b * C + 2 * pass) * HW;   // only read when !isNorm
    const float* p1  = p0 + HW;
    __half2* accp = acc + ((size_t)b * NPAIR + pass) * HW;

    for (int i = threadIdx.x; i < TX * TY; i += TPB) {
        int lx = i % TX, ly = i / TX;
        int gx = tx0 + lx, gy = ty0 + ly;
        if (gx >= W || gy >= H) continue;     // edge tiles
        int p = gy * W + gx;

        float m = __expf(mp[p]);
        float v0, v1;
        if (isNorm) { v0 = m;         v1 = 0.0f;      }
        else        { v0 = p0[p] * m; v1 = p1[p] * m; }

        float ox = (float)gx + fxp[p];
        float oy = (float)gy + fyp[p];
        float x0f = floorf(ox), y0f = floorf(oy);
        int   x0  = (int)x0f,  y0  = (int)y0f;
        float wxh = ox - x0f, wxl = 1.0f - wxh;
        float wyh = oy - y0f, wyl = 1.0f - wyh;
        float w00 = wxl * wyl, w10 = wxh * wyl, w01 = wxl * wyh, w11 = wxh * wyh;

        int wx = x0 - (tx0 - PAD);
        int wy = y0 - (ty0 - PAD);
        if ((unsigned)wx < (unsigned)(WX - 1) && (unsigned)wy < (unsigned)(WY - 1)) {
            int base = (wy << 7) + wx;        // WX == 128
            lds_add(&l0[base],          w00 * v0);
            lds_add(&l0[base + 1],      w10 * v0);
            lds_add(&l0[base + WX],     w01 * v0);
            lds_add(&l0[base + WX + 1], w11 * v0);
            if (!isNorm) {
                lds_add(&l1[base],          w00 * v1);
                lds_add(&l1[base + 1],      w10 * v1);
                lds_add(&l1[base + WX],     w01 * v1);
                lds_add(&l1[base + WX + 1], w11 * v1);
            }
        } else {
            // rare far-flow fallback: direct global pk atomics with image-bounds check
            const int   cxs[4] = { x0, x0 + 1, x0,     x0 + 1 };
            const int   cys[4] = { y0, y0,     y0 + 1, y0 + 1 };
            const float wts[4] = { w00, w10, w01, w11 };
#pragma unroll
            for (int k = 0; k < 4; ++k) {
                int cx = cxs[k], cy = cys[k];
                if ((unsigned)cx < (unsigned)W && (unsigned)cy < (unsigned)H) {
                    __half2 h = __floats2half2_rn(wts[k] * v0, wts[k] * v1);
                    unsafeAtomicAdd(&accp[cy * W + cx], h);
                }
            }
        }
    }
    __syncthreads();

    // Coalesced flush: consecutive lanes -> consecutive half2 addresses (full lines)
    for (int i = threadIdx.x; i < CELLS; i += TPB) {
        int wx = i & (WX - 1), wy = i >> 7;
        int gx = tx0 - PAD + wx, gy = ty0 - PAD + wy;
        float a0 = l0[i], a1 = l1[i];
        bool nz = (a0 != 0.0f) || (a1 != 0.0f);
        bool in = ((unsigned)gx < (unsigned)W) && ((unsigned)gy < (unsigned)H);
        if (in && __any(nz)) {                 // whole-wave zero skip, keep coalescing otherwise
            unsafeAtomicAdd(&accp[gy * W + gx], __floats2half2_rn(a0, a1));
        }
    }
}

__global__ __launch_bounds__(256)
void normalize_tiled(const __half2* __restrict__ acc,
                     float* __restrict__ out)
{
    // one thread per (b, pair, pixel-quad)
    int t = blockIdx.x * blockDim.x + threadIdx.x;
    if (t >= B * 16 * P4) return;
    int p4   = t % P4;
    int rest = t / P4;
    int pr   = rest % 16;
    int b    = rest / 16;

    const float4 araw = *reinterpret_cast<const float4*>(
        acc + ((size_t)b * NPAIR + pr) * HW + (size_t)p4 * 4);
    const float4 nraw = *reinterpret_cast<const float4*>(
        acc + ((size_t)b * NPAIR + 16) * HW + (size_t)p4 * 4);

    __half2 h0 = *reinterpret_cast<const __half2*>(&araw.x);
    __half2 h1 = *reinterpret_cast<const __half2*>(&araw.y);
    __half2 h2 = *reinterpret_cast<const __half2*>(&araw.z);
    __half2 h3 = *reinterpret_cast<const __half2*>(&araw.w);
    __half2 n0 = *reinterpret_cast<const __half2*>(&nraw.x);
    __half2 n1 = *reinterpret_cast<const __half2*>(&nraw.y);
    __half2 n2 = *reinterpret_cast<const __half2*>(&nraw.z);
    __half2 n3 = *reinterpret_cast<const __half2*>(&nraw.w);

    float na = __low2float(n0), nb = __low2float(n1);
    float nc = __low2float(n2), nd = __low2float(n3);
    float r0 = (na == 0.0f) ? 1.0f : 1.0f / na;
    float r1 = (nb == 0.0f) ? 1.0f : 1.0f / nb;
    float r2 = (nc == 0.0f) ? 1.0f : 1.0f / nc;
    float r3 = (nd == 0.0f) ? 1.0f : 1.0f / nd;

    float4 lo = make_float4(__low2float(h0) * r0, __low2float(h1) * r1,
                            __low2float(h2) * r2, __low2float(h3) * r3);
    float4 hi = make_float4(__high2float(h0) * r0, __high2float(h1) * r1,
                            __high2float(h2) * r2, __high2float(h3) * r3);

    float* o0 = out + ((size_t)b * C + 2 * pr)     * HW + (size_t)p4 * 4;
    float* o1 = out + ((size_t)b * C + 2 * pr + 1) * HW + (size_t)p4 * 4;
    *reinterpret_cast<float4*>(o0) = lo;
    *reinterpret_cast<float4*>(o1) = hi;
}

// ---------- fallback path (ws too small): f32 atomics straight into d_out ----------

__global__ __launch_bounds__(256)
void splat_f32(const float* __restrict__ inp,
               const float* __restrict__ flow,
               const float* __restrict__ metric,
               float* __restrict__ out,
               float* __restrict__ norm)
{
    int idx = blockIdx.x * blockDim.x + threadIdx.x;
    if (idx >= NPIX) return;
    int b = idx / HW;
    int p = idx - b * HW;
    int y = p / W;
    int x = p - y * W;

    float fx = flow[(b * 2 + 0) * HW + p];
    float fy = flow[(b * 2 + 1) * HW + p];
    float m  = __expf(metric[b * HW + p]);

    float ox = (float)x + fx, oy = (float)y + fy;
    float x0f = floorf(ox), y0f = floorf(oy);
    int x0 = (int)x0f, y0 = (int)y0f;
    float wx1 = ox - x0f, wx0 = 1.0f - wx1;
    float wy1 = oy - y0f, wy0 = 1.0f - wy1;

    float vm[C];
    const float* inb = inp + (size_t)b * C * HW + p;
#pragma unroll
    for (int c = 0; c < C; ++c) vm[c] = inb[(size_t)c * HW] * m;

    float* outb = out + (size_t)b * C * HW;
    float* nrmb = norm + (size_t)b * HW;

    const int   cxs[4] = { x0, x0 + 1, x0,     x0 + 1 };
    const int   cys[4] = { y0, y0,     y0 + 1, y0 + 1 };
    const float wts[4] = { wx0 * wy0, wx1 * wy0, wx0 * wy1, wx1 * wy1 };

#pragma unroll
    for (int k = 0; k < 4; ++k) {
        int cx = cxs[k], cy = cys[k];
        if (cx < 0 || cx >= W || cy < 0 || cy >= H) continue;
        float wt = wts[k];
        int q = cy * W + cx;
        atomicAdd(&nrmb[q], m * wt);
#pragma unroll
        for (int c = 0; c < C; ++c)
            atomicAdd(&outb[(size_t)c * HW + q], vm[c] * wt);
    }
}

__global__ __launch_bounds__(256)
void normalize_f32(float* __restrict__ out, const float* __restrict__ norm)
{
    int t = blockIdx.x * blockDim.x + threadIdx.x;
    long long base = (long long)t * 4;
    if (base >= (long long)B * C * HW) return;
    long long b = base / ((long long)C * HW);
    long long q = base % HW;

    float4 o = *reinterpret_cast<float4*>(out + base);
    float4 n = *reinterpret_cast<const float4*>(norm + b * HW + q);
    o.x /= (n.x == 0.0f ? 1.0f : n.x);
    o.y /= (n.y == 0.0f ? 1.0f : n.y);
    o.z /= (n.z == 0.0f ? 1.0f : n.z);
    o.w /= (n.w == 0.0f ? 1.0f : n.w);
    *reinterpret_cast<float4*>(out + base) = o;
}

extern "C" void kernel_launch(void* const* d_in, const int* in_sizes, int n_in,
                              void* d_out, int out_size, void* d_ws, size_t ws_size,
                              hipStream_t stream) {
    const float* tenInput  = (const float*)d_in[0];
    const float* tenFlow   = (const float*)d_in[1];
    const float* tenMetric = (const float*)d_in[2];
    float* out = (float*)d_out;

    const size_t accBytes = (size_t)B * NPAIR * HW * sizeof(__half2);  // ~142 MB

    if (ws_size >= accBytes) {
        __half2* acc = (__half2*)d_ws;
        hipMemsetAsync(acc, 0, accBytes, stream);

        dim3 grid(TILES_X * TILES_Y, B, NPAIR);
        splat_tiled<<<grid, TPB, 0, stream>>>(tenInput, tenFlow, tenMetric, acc);

        int total = B * 16 * P4;
        normalize_tiled<<<(total + 255) / 256, 256, 0, stream>>>(acc, out);
    } else {
        float* norm = (float*)d_ws;
        hipMemsetAsync(out, 0, (size_t)B * C * HW * sizeof(float), stream);
        hipMemsetAsync(norm, 0, (size_t)NPIX * sizeof(float), stream);

        int threads = 256;
        int blocks = (NPIX + threads - 1) / threads;
        splat_f32<<<blocks, threads, 0, stream>>>(tenInput, tenFlow, tenMetric, out, norm);

        long long total = (long long)B * C * HW / 4;
        normalize_f32<<<(int)((total + threads - 1) / threads), threads, 0, stream>>>(out, norm);
    }
}